// Round 11
// baseline (522.036 us; speedup 1.0000x reference)
//
#include <hip/hip_runtime.h>

#define BB 32
#define DD 400
#define KK 200
#define NN (BB*KK)
#define NBINS 512

typedef float f2 __attribute__((ext_vector_type(2)));
typedef _Float16 half_t;
typedef _Float16 f16x2 __attribute__((ext_vector_type(2)));

__device__ __forceinline__ float dot2(f16x2 w, f16x2 v, float acc) {
  return __builtin_amdgcn_fdot2(w, v, acc, false);
}

__device__ __forceinline__ float fast_sigmoid(float x) {
  float e = __builtin_amdgcn_exp2f(-1.4426950408889634f * x);
  return __builtin_amdgcn_rcpf(1.0f + e);
}
__device__ __forceinline__ float fast_tanh(float x) {
  float e = __builtin_amdgcn_exp2f(-2.8853900817779268f * x);
  return 2.0f * __builtin_amdgcn_rcpf(1.0f + e) - 1.0f;
}

// quad_perm broadcast P within each aligned 4-lane quad (VALU pipe)
#define QPERM(v, P) __int_as_float(__builtin_amdgcn_mov_dpp(__float_as_int(v), (P)*0x55, 0xF, 0xF, true))
// ROW_HALF_MIRROR: lane i reads lane i^7 within each 8-lane half-row (VALU pipe)
#define HMIRROR(v) __int_as_float(__builtin_amdgcn_mov_dpp(__float_as_int(v), 0x141, 0xF, 0xF, true))

// x (B, D, K) -> xt[(b*K+k)*D + t] = x[b][t][k]
__global__ __launch_bounds__(256) void transpose_x(const float* __restrict__ x,
                                                   float* __restrict__ xt) {
  __shared__ float tile[32][33];
  int b = blockIdx.x, t0 = blockIdx.y * 32, k0 = blockIdx.z * 32;
  int tx = threadIdx.x, ty = threadIdx.y;
#pragma unroll
  for (int i = 0; i < 32; i += 8) {
    int t = t0 + ty + i, k = k0 + tx;
    tile[ty + i][tx] = (t < DD && k < KK) ? x[((size_t)b * DD + t) * KK + k] : 0.0f;
  }
  __syncthreads();
#pragma unroll
  for (int i = 0; i < 32; i += 8) {
    int k = k0 + ty + i, t = t0 + tx;
    if (k < KK && t < DD) xt[((size_t)b * KK + k) * DD + t] = tile[tx][ty + i];
  }
}

// first zero index (else D) per sequence + length histogram
__global__ __launch_bounds__(64) void compute_lengths(const float* __restrict__ xt,
                                                      int* __restrict__ lengths,
                                                      int* __restrict__ hist) {
  int n = blockIdx.x, lane = threadIdx.x;
  int m = DD;
  for (int t = lane; t < DD; t += 64) {
    if (xt[(size_t)n * DD + t] == 0.0f) { m = t; break; }
  }
#pragma unroll
  for (int off = 1; off < 64; off <<= 1) {
    int o = __shfl_xor(m, off, 64);
    m = (o < m) ? o : m;
  }
  if (lane == 0) {
    lengths[n] = m;
    atomicAdd(&hist[m], 1);
  }
}

// wave-parallel exclusive prefix scan over 512 bins
__global__ __launch_bounds__(64) void scan_offsets(const int* __restrict__ hist,
                                                   int* __restrict__ offs) {
  int lane = threadIdx.x;
  int v[8], tot = 0;
#pragma unroll
  for (int i = 0; i < 8; ++i) { v[i] = tot; tot += hist[lane * 8 + i]; }
  int incl = tot;
#pragma unroll
  for (int off = 1; off < 64; off <<= 1) {
    int oth = __shfl_up(incl, off, 64);
    if (lane >= off) incl += oth;
  }
  int excl = incl - tot;
#pragma unroll
  for (int i = 0; i < 8; ++i) offs[lane * 8 + i] = excl + v[i];
}

__global__ __launch_bounds__(256) void scatter_sort(const int* __restrict__ lengths,
                                                    int* __restrict__ offs,
                                                    int* __restrict__ order,
                                                    int* __restrict__ len_sorted) {
  int n = blockIdx.x * 256 + threadIdx.x;
  if (n >= NN) return;
  int len = lengths[n];
  int pos = atomicAdd(&offs[len], 1);
  order[pos] = n;
  len_sorted[pos] = len;
}

// ===== fused bidirectional GRU scan =====
// 8 lanes per SEQUENCE; each lane li owns hidden unit li of BOTH directions,
// run as two independent in-lane chains (fwd & bwd) -> chain latency of one
// hides under the other; wave count = nseq/8 = 800 <= 1024 SIMDs.
// Buffer layout [octet][t][dir][64]: stores are lane-linear 128B contiguous per
// chain per step; next layer loads 2 x 16B dwordx4 per chain per step.
// h-exchange: all-DPP (HMIRROR + QPERM); wAB.y uses Whh column (qb+P)^7.
template <int IN_DIM>
__global__ __launch_bounds__(64) void gru_bidir(
    const void* __restrict__ in, half_t* __restrict__ out,
    const int* __restrict__ len_sorted, const int* __restrict__ order,
    const float* __restrict__ Wih, const float* __restrict__ Whh,
    const float* __restrict__ bih, const float* __restrict__ bhh, int nseq) {
  int W = nseq >> 3;                 // nseq is a multiple of 8
  int p = blockIdx.x;
  if (p >= W) return;
  int o = W - 1 - p;                 // longest octets start first
  int lane = threadIdx.x & 63;
  int s8 = lane >> 3, li = lane & 7;
  int sg = o * 8 + s8;
  int len = len_sorted[sg];
  int qb = li & 4;

  f2 wABf[3][4], wABb[3][4];
  f16x2 wif[3][8], wib[3][8];
  float w1f[3], w1b[3];
  float bsf[3], bsb[3], bh2f, bh2b;
#pragma unroll
  for (int gt = 0; gt < 3; ++gt) {
    int rf = gt * 8 + li, rb = 24 + gt * 8 + li;
    if constexpr (IN_DIM == 16) {
#pragma unroll
      for (int q = 0; q < 8; ++q) {
        f16x2 a; a.x = (half_t)Wih[rf * 16 + 2*q]; a.y = (half_t)Wih[rf * 16 + 2*q + 1];
        wif[gt][q] = a;
        f16x2 b; b.x = (half_t)Wih[rb * 16 + 2*q]; b.y = (half_t)Wih[rb * 16 + 2*q + 1];
        wib[gt][q] = b;
      }
    } else {
      w1f[gt] = Wih[rf];
      w1b[gt] = Wih[rb];
    }
#pragma unroll
    for (int P = 0; P < 4; ++P) {
      f2 a; a.x = Whh[rf * 8 + qb + P]; a.y = Whh[rf * 8 + ((qb + P) ^ 7)];
      wABf[gt][P] = a;
      f2 b; b.x = Whh[rb * 8 + qb + P]; b.y = Whh[rb * 8 + ((qb + P) ^ 7)];
      wABb[gt][P] = b;
    }
    bsf[gt] = bih[rf] + ((gt < 2) ? bhh[rf] : 0.0f);
    bsb[gt] = bih[rb] + ((gt < 2) ? bhh[rb] : 0.0f);
    if (gt == 2) { bh2f = bhh[rf]; bh2b = bhh[rb]; }
  }

  float hf = 0.0f, hb = 0.0f;

  // input pointers
  const float* pxf1 = nullptr; const float* pxb1 = nullptr;
  const half_t* pxf = nullptr; const half_t* pxb = nullptr;
  if constexpr (IN_DIM == 1) {
    const float* base = (const float*)in + (size_t)order[sg] * DD;
    pxf1 = base;
    pxb1 = base + (len - 1);
  } else {
    const half_t* slab = (const half_t*)in + (size_t)o * DD * 128;
    pxf = slab + s8 * 8;
    pxb = slab + (size_t)(len - 1) * 128 + s8 * 8;
  }
  // output pointers (lane-linear within [t][dir][64] blocks)
  half_t* ob  = out + (size_t)o * DD * 128;
  half_t* pwf = ob + lane;                               // dir0 block of t
  half_t* pwb = ob + (size_t)(len - 1) * 128 + 64 + lane; // dir1 block of len-1-t

  // one chain's step epilogue (independent register state per chain)
  auto core1 = [&](float& h, f2 (&wAB)[3][4], float bh2v,
                   float a0, float a1, float a2, half_t*& pw, ptrdiff_t ws) {
    float hm = HMIRROR(h);
    float hq0 = QPERM(h, 0), hq1 = QPERM(h, 1), hq2 = QPERM(h, 2), hq3 = QPERM(h, 3);
    float hx0 = QPERM(hm, 0), hx1 = QPERM(hm, 1), hx2 = QPERM(hm, 2), hx3 = QPERM(hm, 3);
    f2 u0; u0.x = hq0; u0.y = hx0;
    f2 u1; u1.x = hq1; u1.y = hx1;
    f2 u2; u2.x = hq2; u2.y = hx2;
    f2 u3; u3.x = hq3; u3.y = hx3;
    f2 c0a = wAB[0][0] * u0; c0a += wAB[0][1] * u1;
    f2 c0b = wAB[0][2] * u2; c0b += wAB[0][3] * u3;
    f2 c0 = c0a + c0b;
    f2 c1a = wAB[1][0] * u0; c1a += wAB[1][1] * u1;
    f2 c1b = wAB[1][2] * u2; c1b += wAB[1][3] * u3;
    f2 c1 = c1a + c1b;
    f2 c2a = wAB[2][0] * u0; c2a += wAB[2][1] * u1;
    f2 c2b = wAB[2][2] * u2; c2b += wAB[2][3] * u3;
    f2 c2 = c2a + c2b;
    float r = fast_sigmoid(a0 + c0.x + c0.y);
    float z = fast_sigmoid(a1 + c1.x + c1.y);
    float n = fast_tanh(a2 + r * (bh2v + c2.x + c2.y));
    h = z * (h - n) + n;
    *pw = (half_t)h; pw += ws;
  };

  if constexpr (IN_DIM == 1) {
    float ff0, ff1, ff2, ff3, bb0, bb1, bb2, bb3;
    auto ld = [&](float& F_, float& B_) { F_ = *pxf1++; B_ = *pxb1--; };
    auto st = [&](float& F_, float& B_, bool pf) {
      float a0f = fmaf(w1f[0], F_, bsf[0]);
      float a1f = fmaf(w1f[1], F_, bsf[1]);
      float a2f = fmaf(w1f[2], F_, bsf[2]);
      float a0b = fmaf(w1b[0], B_, bsb[0]);
      float a1b = fmaf(w1b[1], B_, bsb[1]);
      float a2b = fmaf(w1b[2], B_, bsb[2]);
      if (pf) ld(F_, B_);
      core1(hf, wABf, bh2f, a0f, a1f, a2f, pwf, 128);
      core1(hb, wABb, bh2b, a0b, a1b, a2b, pwb, -128);
    };
    ld(ff0, bb0); ld(ff1, bb1); ld(ff2, bb2); ld(ff3, bb3);
    int t = 0;
    for (; t + 4 <= len; t += 4) {
      st(ff0, bb0, true); st(ff1, bb1, true); st(ff2, bb2, true); st(ff3, bb3, true);
    }
    int rem = len - t;
    if (rem > 0) st(ff0, bb0, false);
    if (rem > 1) st(ff1, bb1, false);
    if (rem > 2) st(ff2, bb2, false);
  } else {
    uint4 F0[2], F1[2], F2[2], F3[2], B0[2], B1[2], B2[2], B3[2];
    auto ld = [&](uint4 (&F_)[2], uint4 (&B_)[2]) {
      const uint4* qf = reinterpret_cast<const uint4*>(pxf);
      F_[0] = qf[0]; F_[1] = qf[8];    // +128 B = bwd-half block of same t
      pxf += 128;
      const uint4* qbp = reinterpret_cast<const uint4*>(pxb);
      B_[0] = qbp[0]; B_[1] = qbp[8];
      pxb -= 128;
    };
    auto gi3 = [&](uint4 (&X_)[2], f16x2 (&wi)[3][8], const float* bsv,
                   float& a0, float& a1, float& a2) {
      a0 = bsv[0]; a1 = bsv[1]; a2 = bsv[2];
#pragma unroll
      for (int q = 0; q < 2; ++q) {
        f16x2 p0 = __builtin_bit_cast(f16x2, X_[q].x);
        f16x2 p1 = __builtin_bit_cast(f16x2, X_[q].y);
        f16x2 p2 = __builtin_bit_cast(f16x2, X_[q].z);
        f16x2 p3 = __builtin_bit_cast(f16x2, X_[q].w);
        a0 = dot2(wi[0][4*q], p0, a0); a0 = dot2(wi[0][4*q+1], p1, a0);
        a0 = dot2(wi[0][4*q+2], p2, a0); a0 = dot2(wi[0][4*q+3], p3, a0);
        a1 = dot2(wi[1][4*q], p0, a1); a1 = dot2(wi[1][4*q+1], p1, a1);
        a1 = dot2(wi[1][4*q+2], p2, a1); a1 = dot2(wi[1][4*q+3], p3, a1);
        a2 = dot2(wi[2][4*q], p0, a2); a2 = dot2(wi[2][4*q+1], p1, a2);
        a2 = dot2(wi[2][4*q+2], p2, a2); a2 = dot2(wi[2][4*q+3], p3, a2);
      }
    };
    auto st = [&](uint4 (&F_)[2], uint4 (&B_)[2], bool pf) {
      float a0f, a1f, a2f, a0b, a1b, a2b;
      gi3(F_, wif, bsf, a0f, a1f, a2f);
      gi3(B_, wib, bsb, a0b, a1b, a2b);
      if (pf) ld(F_, B_);
      core1(hf, wABf, bh2f, a0f, a1f, a2f, pwf, 128);
      core1(hb, wABb, bh2b, a0b, a1b, a2b, pwb, -128);
    };
    ld(F0, B0); ld(F1, B1); ld(F2, B2); ld(F3, B3);
    int t = 0;
    for (; t + 4 <= len; t += 4) {
      st(F0, B0, true); st(F1, B1, true); st(F2, B2, true); st(F3, B3, true);
    }
    int rem = len - t;
    if (rem > 0) st(F0, B0, false);
    if (rem > 1) st(F1, B1, false);
    if (rem > 2) st(F2, B2, false);
  }
}

// last layer forward: no per-step stores, feat only
__global__ __launch_bounds__(64) void gru_fwd_last(
    const half_t* __restrict__ in, float* __restrict__ feat,
    const int* __restrict__ len_sorted, const int* __restrict__ order,
    const float* __restrict__ Wih, const float* __restrict__ Whh,
    const float* __restrict__ bih, const float* __restrict__ bhh, int nseq) {
  int W = nseq >> 3;
  int p = blockIdx.x;
  if (p >= W) return;
  int o = W - 1 - p;
  int lane = threadIdx.x & 63;
  int s8 = lane >> 3, li = lane & 7;
  int sg = o * 8 + s8;
  int len = len_sorted[sg];
  int qb = li & 4;

  f2 wAB[3][4];
  f16x2 wi2[3][8];
  float bs[3], bh2v;
#pragma unroll
  for (int gt = 0; gt < 3; ++gt) {
    int row = gt * 8 + li;  // dir 0
#pragma unroll
    for (int q = 0; q < 8; ++q) {
      f16x2 w; w.x = (half_t)Wih[row * 16 + 2*q]; w.y = (half_t)Wih[row * 16 + 2*q + 1];
      wi2[gt][q] = w;
    }
#pragma unroll
    for (int P = 0; P < 4; ++P) {
      f2 w; w.x = Whh[row * 8 + qb + P]; w.y = Whh[row * 8 + ((qb + P) ^ 7)];
      wAB[gt][P] = w;
    }
    bs[gt] = bih[row] + ((gt < 2) ? bhh[row] : 0.0f);
    if (gt == 2) bh2v = bhh[row];
  }

  float h = 0.0f;
  const half_t* pxf = in + (size_t)o * DD * 128 + s8 * 8;

  auto core1 = [&](float a0, float a1, float a2) {
    float hm = HMIRROR(h);
    float hq0 = QPERM(h, 0), hq1 = QPERM(h, 1), hq2 = QPERM(h, 2), hq3 = QPERM(h, 3);
    float hx0 = QPERM(hm, 0), hx1 = QPERM(hm, 1), hx2 = QPERM(hm, 2), hx3 = QPERM(hm, 3);
    f2 u0; u0.x = hq0; u0.y = hx0;
    f2 u1; u1.x = hq1; u1.y = hx1;
    f2 u2; u2.x = hq2; u2.y = hx2;
    f2 u3; u3.x = hq3; u3.y = hx3;
    f2 c0a = wAB[0][0] * u0; c0a += wAB[0][1] * u1;
    f2 c0b = wAB[0][2] * u2; c0b += wAB[0][3] * u3;
    f2 c0 = c0a + c0b;
    f2 c1a = wAB[1][0] * u0; c1a += wAB[1][1] * u1;
    f2 c1b = wAB[1][2] * u2; c1b += wAB[1][3] * u3;
    f2 c1 = c1a + c1b;
    f2 c2a = wAB[2][0] * u0; c2a += wAB[2][1] * u1;
    f2 c2b = wAB[2][2] * u2; c2b += wAB[2][3] * u3;
    f2 c2 = c2a + c2b;
    float r = fast_sigmoid(a0 + c0.x + c0.y);
    float z = fast_sigmoid(a1 + c1.x + c1.y);
    float n = fast_tanh(a2 + r * (bh2v + c2.x + c2.y));
    h = z * (h - n) + n;
  };

  uint4 F0[2], F1[2], F2[2], F3[2];
  auto ld = [&](uint4 (&F_)[2]) {
    const uint4* q = reinterpret_cast<const uint4*>(pxf);
    F_[0] = q[0]; F_[1] = q[8];
    pxf += 128;
  };
  auto st = [&](uint4 (&F_)[2], bool pf) {
    float a0 = bs[0], a1 = bs[1], a2 = bs[2];
#pragma unroll
    for (int q = 0; q < 2; ++q) {
      f16x2 p0 = __builtin_bit_cast(f16x2, F_[q].x);
      f16x2 p1 = __builtin_bit_cast(f16x2, F_[q].y);
      f16x2 p2 = __builtin_bit_cast(f16x2, F_[q].z);
      f16x2 p3 = __builtin_bit_cast(f16x2, F_[q].w);
      a0 = dot2(wi2[0][4*q], p0, a0); a0 = dot2(wi2[0][4*q+1], p1, a0);
      a0 = dot2(wi2[0][4*q+2], p2, a0); a0 = dot2(wi2[0][4*q+3], p3, a0);
      a1 = dot2(wi2[1][4*q], p0, a1); a1 = dot2(wi2[1][4*q+1], p1, a1);
      a1 = dot2(wi2[1][4*q+2], p2, a1); a1 = dot2(wi2[1][4*q+3], p3, a1);
      a2 = dot2(wi2[2][4*q], p0, a2); a2 = dot2(wi2[2][4*q+1], p1, a2);
      a2 = dot2(wi2[2][4*q+2], p2, a2); a2 = dot2(wi2[2][4*q+3], p3, a2);
    }
    if (pf) ld(F_);
    core1(a0, a1, a2);
  };
  ld(F0); ld(F1); ld(F2); ld(F3);
  int t = 0;
  for (; t + 4 <= len; t += 4) {
    st(F0, true); st(F1, true); st(F2, true); st(F3, true);
  }
  int rem = len - t;
  if (rem > 0) st(F0, false);
  if (rem > 1) st(F1, false);
  if (rem > 2) st(F2, false);

  feat[(size_t)order[sg] * 16 + li] = h;
}

// last layer, bwd direction: only t = len-1 matters and h0 = 0 => gh = bhh
__global__ __launch_bounds__(256) void bwd_last(
    const half_t* __restrict__ in, float* __restrict__ feat,
    const int* __restrict__ len_sorted, const int* __restrict__ order,
    const float* __restrict__ Wih, const float* __restrict__ bih,
    const float* __restrict__ bhh, int nseq) {
  int tid = blockIdx.x * blockDim.x + threadIdx.x;
  int sg = tid >> 3, li = tid & 7;
  if (sg >= nseq) return;
  int len = len_sorted[sg];
  int o = sg >> 3;
  const half_t* xp = in + ((size_t)o * DD + (len - 1)) * 128 + (sg & 7) * 8;
  float xv[16];
#pragma unroll
  for (int j = 0; j < 8; ++j) { xv[j] = (float)xp[j]; xv[8 + j] = (float)xp[64 + j]; }
  float a[3], bh[3];
#pragma unroll
  for (int gt = 0; gt < 3; ++gt) {
    int row = 24 + gt * 8 + li;  // dir=1 rows
    const float* wp = Wih + row * 16;
    float acc = bih[row];
#pragma unroll
    for (int j = 0; j < 16; ++j) acc = fmaf(wp[j], xv[j], acc);
    a[gt] = acc;
    bh[gt] = bhh[row];
  }
  float r = fast_sigmoid(a[0] + bh[0]);
  float z = fast_sigmoid(a[1] + bh[1]);
  float n = fast_tanh(a[2] + r * bh[2]);
  float h = (1.0f - z) * n;
  feat[(size_t)order[sg] * 16 + 8 + li] = h;
}

__global__ __launch_bounds__(256) void head_kernel(
    const float* __restrict__ feat, const float* __restrict__ w1,
    const float* __restrict__ b1, const float* __restrict__ w2,
    const float* __restrict__ b2, float* __restrict__ out) {
  int n = blockIdx.x * blockDim.x + threadIdx.x;
  if (n >= NN) return;
  float f[16];
  const float4* p = reinterpret_cast<const float4*>(feat + (size_t)n * 16);
#pragma unroll
  for (int q = 0; q < 4; ++q) {
    float4 v = p[q];
    f[4*q] = v.x; f[4*q+1] = v.y; f[4*q+2] = v.z; f[4*q+3] = v.w;
  }
  float y[8];
#pragma unroll
  for (int o = 0; o < 8; ++o) {
    float s = b1[o];
#pragma unroll
    for (int j = 0; j < 16; ++j) s += f[j] * w1[o * 16 + j];
    y[o] = (s > 0.0f) ? s : 0.2f * s;
  }
#pragma unroll
  for (int o2 = 0; o2 < 8; ++o2) {
    float s = b2[o2];
#pragma unroll
    for (int o = 0; o < 8; ++o) s += y[o] * w2[o2 * 8 + o];
    out[(size_t)n * 8 + o2] = s;
  }
}

extern "C" void kernel_launch(void* const* d_in, const int* in_sizes, int n_in,
                              void* d_out, int out_size, void* d_ws, size_t ws_size,
                              hipStream_t stream) {
  const float* x      = (const float*)d_in[0];
  const float* w_ih0  = (const float*)d_in[1];
  const float* w_hh0  = (const float*)d_in[2];
  const float* b_ih0  = (const float*)d_in[3];
  const float* b_hh0  = (const float*)d_in[4];
  const float* w_ih   = (const float*)d_in[5];
  const float* w_hh   = (const float*)d_in[6];
  const float* b_ih   = (const float*)d_in[7];
  const float* b_hh   = (const float*)d_in[8];
  const float* lin1_w = (const float*)d_in[9];
  const float* lin1_b = (const float*)d_in[10];
  const float* lin2_w = (const float*)d_in[11];
  const float* lin2_b = (const float*)d_in[12];
  float* out = (float*)d_out;

  char* ws = (char*)d_ws;
  size_t off = 0;
  auto alloc = [&](size_t bytes) -> void* {
    void* p = ws + off;
    off += (bytes + 255) & ~(size_t)255;
    return p;
  };
  alloc(2048);  // front guard (backward prefetch overrun)
  float* xt         = (float*)alloc((size_t)NN * DD * sizeof(float) + 2048);
  int*   lengths    = (int*)  alloc((size_t)NN * sizeof(int));
  int*   hist       = (int*)  alloc(NBINS * sizeof(int));
  int*   offs       = (int*)  alloc(NBINS * sizeof(int));
  int*   order      = (int*)  alloc((size_t)NN * sizeof(int));
  int*   len_sorted = (int*)  alloc((size_t)NN * sizeof(int));
  float* feat       = (float*)alloc((size_t)NN * 16 * sizeof(float));
  size_t base = off;
  size_t per_seq = (size_t)DD * 16 * sizeof(half_t) * 2 + 1024;  // two f16 buffers
  int Nc = NN;
  if (base + (size_t)NN * per_seq + 16384 > ws_size) {
    size_t avail = (ws_size > base + 16384) ? (ws_size - base - 16384) : 0;
    size_t nc = avail / per_seq;
    if (nc < 8) nc = 8;
    if (nc > (size_t)NN) nc = NN;
    Nc = (int)(nc & ~(size_t)7);  // multiple of 8 (octet granularity)
  }
  alloc(2048);  // guard before bufA
  half_t* bufA = (half_t*)alloc((size_t)Nc * DD * 16 * sizeof(half_t) + 2048);
  half_t* bufB = (half_t*)alloc((size_t)Nc * DD * 16 * sizeof(half_t) + 2048);

  hipMemsetAsync(hist, 0, NBINS * sizeof(int), stream);
  dim3 gT(BB, (DD + 31) / 32, (KK + 31) / 32), bT(32, 8, 1);
  hipLaunchKernelGGL(transpose_x, gT, bT, 0, stream, x, xt);
  hipLaunchKernelGGL(compute_lengths, dim3(NN), dim3(64), 0, stream, xt, lengths, hist);
  hipLaunchKernelGGL(scan_offsets, dim3(1), dim3(64), 0, stream, hist, offs);
  hipLaunchKernelGGL(scatter_sort, dim3((NN + 255) / 256), dim3(256), 0, stream,
                     lengths, offs, order, len_sorted);

  for (int s0 = 0; s0 < NN; s0 += Nc) {
    int ns = (NN - s0 < Nc) ? (NN - s0) : Nc;
    int Wb = ns / 8;                      // one wave (64 thr) per 8 sequences
    int blk1 = (ns * 8 + 255) / 256;      // bwd_last
    gru_bidir<1><<<Wb, 64, 0, stream>>>(
        (const void*)xt, bufA, len_sorted + s0, order + s0,
        w_ih0, w_hh0, b_ih0, b_hh0, ns);
    gru_bidir<16><<<Wb, 64, 0, stream>>>(
        (const void*)bufA, bufB, len_sorted + s0, order + s0,
        w_ih + 0 * 2 * 24 * 16, w_hh + 0 * 2 * 24 * 8,
        b_ih + 0 * 2 * 24, b_hh + 0 * 2 * 24, ns);
    gru_bidir<16><<<Wb, 64, 0, stream>>>(
        (const void*)bufB, bufA, len_sorted + s0, order + s0,
        w_ih + 1 * 2 * 24 * 16, w_hh + 1 * 2 * 24 * 8,
        b_ih + 1 * 2 * 24, b_hh + 1 * 2 * 24, ns);
    hipLaunchKernelGGL(gru_fwd_last, dim3(Wb), dim3(64), 0, stream,
        bufA, feat, len_sorted + s0, order + s0,
        w_ih + 2 * 2 * 24 * 16, w_hh + 2 * 2 * 24 * 8,
        b_ih + 2 * 2 * 24, b_hh + 2 * 2 * 24, ns);
    hipLaunchKernelGGL(bwd_last, dim3(blk1), dim3(256), 0, stream,
                       bufA, feat, len_sorted + s0, order + s0,
                       w_ih + 2 * 2 * 24 * 16, b_ih + 2 * 2 * 24, b_hh + 2 * 2 * 24, ns);
  }
  hipLaunchKernelGGL(head_kernel, dim3((NN + 255) / 256), dim3(256), 0, stream,
                     feat, lin1_w, lin1_b, lin2_w, lin2_b, out);
}

// Round 12
// 382.580 us; speedup vs baseline: 1.3645x; 1.3645x over previous
//
#include <hip/hip_runtime.h>

#define BB 32
#define DD 400
#define KK 200
#define NN (BB*KK)
#define NBINS 512
#define NSIMD 1024  // 256 CU x 4 SIMD

typedef _Float16 half_t;
typedef _Float16 f16x2 __attribute__((ext_vector_type(2)));

__device__ __forceinline__ float dot2(f16x2 w, f16x2 v, float acc) {
  return __builtin_amdgcn_fdot2(w, v, acc, false);
}
__device__ __forceinline__ f16x2 bc16(int v) { return __builtin_bit_cast(f16x2, v); }
__device__ __forceinline__ int pkh(float a, float b) {
  return __builtin_bit_cast(int, __builtin_amdgcn_cvt_pkrtz(a, b));
}

__device__ __forceinline__ float fast_sigmoid(float x) {
  float e = __builtin_amdgcn_exp2f(-1.4426950408889634f * x);
  return __builtin_amdgcn_rcpf(1.0f + e);
}
__device__ __forceinline__ float fast_tanh(float x) {
  float e = __builtin_amdgcn_exp2f(-2.8853900817779268f * x);
  return 2.0f * __builtin_amdgcn_rcpf(1.0f + e) - 1.0f;
}

// quad_perm broadcast P within each aligned 4-lane quad (VALU pipe), int form
#define QPERMI(v, P) __builtin_amdgcn_mov_dpp((v), (P)*0x55, 0xF, 0xF, true)
// ROW_HALF_MIRROR: lane i reads lane i^7 within each 8-lane half-row (VALU pipe)
#define HMIRROR(v) __int_as_float(__builtin_amdgcn_mov_dpp(__float_as_int(v), 0x141, 0xF, 0xF, true))

// x (B, D, K) -> xt[(b*K+k)*D + t] = x[b][t][k]
__global__ __launch_bounds__(256) void transpose_x(const float* __restrict__ x,
                                                   float* __restrict__ xt) {
  __shared__ float tile[32][33];
  int b = blockIdx.x, t0 = blockIdx.y * 32, k0 = blockIdx.z * 32;
  int tx = threadIdx.x, ty = threadIdx.y;
#pragma unroll
  for (int i = 0; i < 32; i += 8) {
    int t = t0 + ty + i, k = k0 + tx;
    tile[ty + i][tx] = (t < DD && k < KK) ? x[((size_t)b * DD + t) * KK + k] : 0.0f;
  }
  __syncthreads();
#pragma unroll
  for (int i = 0; i < 32; i += 8) {
    int k = k0 + ty + i, t = t0 + tx;
    if (k < KK && t < DD) xt[((size_t)b * KK + k) * DD + t] = tile[tx][ty + i];
  }
}

// first zero index (else D) per sequence + length histogram
__global__ __launch_bounds__(64) void compute_lengths(const float* __restrict__ xt,
                                                      int* __restrict__ lengths,
                                                      int* __restrict__ hist) {
  int n = blockIdx.x, lane = threadIdx.x;
  int m = DD;
  for (int t = lane; t < DD; t += 64) {
    if (xt[(size_t)n * DD + t] == 0.0f) { m = t; break; }
  }
#pragma unroll
  for (int off = 1; off < 64; off <<= 1) {
    int o = __shfl_xor(m, off, 64);
    m = (o < m) ? o : m;
  }
  if (lane == 0) {
    lengths[n] = m;
    atomicAdd(&hist[m], 1);
  }
}

// wave-parallel exclusive prefix scan over 512 bins (8 bins/lane + shfl scan)
__global__ __launch_bounds__(64) void scan_offsets(const int* __restrict__ hist,
                                                   int* __restrict__ offs) {
  int lane = threadIdx.x;
  int v[8], tot = 0;
#pragma unroll
  for (int i = 0; i < 8; ++i) { v[i] = tot; tot += hist[lane * 8 + i]; }
  int incl = tot;
#pragma unroll
  for (int off = 1; off < 64; off <<= 1) {
    int oth = __shfl_up(incl, off, 64);
    if (lane >= off) incl += oth;
  }
  int excl = incl - tot;
#pragma unroll
  for (int i = 0; i < 8; ++i) offs[lane * 8 + i] = excl + v[i];
}

__global__ __launch_bounds__(256) void scatter_sort(const int* __restrict__ lengths,
                                                    int* __restrict__ offs,
                                                    int* __restrict__ order,
                                                    int* __restrict__ len_sorted) {
  int n = blockIdx.x * 256 + threadIdx.x;
  if (n >= NN) return;
  int len = lengths[n];
  int pos = atomicAdd(&offs[len], 1);
  order[pos] = n;
  len_sorted[pos] = len;
}

// SIMD-aware wave->octet mapping (1 wave per block; XCD round-robin means
// p and p+NSIMD co-reside). Singles get longest octets; pairs sum ~constant.
__device__ __forceinline__ int octet_of_wave(int p, int W) {
  int E = W - NSIMD;
  if (E <= 0) return W - 1 - p;                 // all singles: desc
  if (p >= NSIMD) return p - NSIMD;             // pair minor: shortest E
  if (p >= E) return W - 1 - (p - E);           // singles: longest
  return (W - 1 - NSIMD + E) - p;               // pair major
}

// 8 lanes per (sorted-seq, dir); lane li owns hidden unit li. 1 wave per block.
// h-exchange + gh fully packed-f16: hp = cvt_pk(h, HMIRROR(h)); 4 quad_perm DPP
// deliver all 8 h values as f16x2; gh = 4-deep v_dot2_f32_f16 chain per gate.
// (GRU recurrence is contractive -> f16 h inside the Whh product is safe.)
// Inter-layer streams f16; gi dots via v_dot2_f32_f16. 4-step register prefetch.
template <int IN_DIM, bool IND_IN, bool WRITE_SEQ, bool FWD_ONLY>
__global__ __launch_bounds__(64) void gru_scan(
    const void* __restrict__ in, half_t* __restrict__ out, float* __restrict__ feat,
    const int* __restrict__ len_sorted, const int* __restrict__ order,
    const float* __restrict__ Wih, const float* __restrict__ Whh,
    const float* __restrict__ bih, const float* __restrict__ bhh, int nseq) {
  int p = blockIdx.x;                 // one wave per block
  int lane = threadIdx.x & 63;
  int G = FWD_ONLY ? nseq : nseq * 2;
  int W = (G + 7) >> 3;
  if (p >= W) return;
  int o = octet_of_wave(p, W);
  int gidx = o * 8 + (lane >> 3);
  int li = lane & 7;
  if (gidx >= G) return;
  int sg  = FWD_ONLY ? gidx : (gidx >> 1);
  int dir = FWD_ONLY ? 0 : (gidx & 1);
  int len = len_sorted[sg];

  int qb = li & 4;
  int wp[3][4];       // packed f16x2 {Whh[.,qb+P], Whh[.,(qb+P)^7]}
  f16x2 wi2[3][8];
  float wi1[3];
  float bs[3], bh2;   // bs[0..1] = bih+bhh, bs[2] = bih; bh2 = bhh n-gate
#pragma unroll
  for (int gt = 0; gt < 3; ++gt) {
    int row = dir * 24 + gt * 8 + li;
    if constexpr (IN_DIM == 16) {
#pragma unroll
      for (int q = 0; q < 8; ++q) {
        f16x2 w;
        w.x = (half_t)Wih[row * 16 + 2 * q];
        w.y = (half_t)Wih[row * 16 + 2 * q + 1];
        wi2[gt][q] = w;
      }
    } else {
      wi1[gt] = Wih[row];
    }
#pragma unroll
    for (int P = 0; P < 4; ++P)
      wp[gt][P] = pkh(Whh[row * 8 + qb + P], Whh[row * 8 + ((qb + P) ^ 7)]);
    bs[gt] = bih[row] + ((gt < 2) ? bhh[row] : 0.0f);
    if (gt == 2) bh2 = bhh[row];
  }

  int steps = len;  // >= 200 always
  float h = 0.0f;

  const float* px = nullptr;
  const half_t* pxh = nullptr;
  ptrdiff_t xstep;
  if constexpr (IN_DIM == 1) {
    const float* basep = (const float*)in + (IND_IN ? (size_t)order[sg] * DD : (size_t)sg * DD);
    px = basep + ((dir == 0) ? 0 : (len - 1));
    xstep = (dir == 0) ? 1 : -1;
  } else {
    const half_t* basep = (const half_t*)in + (size_t)sg * DD * 16;
    pxh = basep + (size_t)((dir == 0) ? 0 : (len - 1)) * 16;
    xstep = (dir == 0) ? 16 : -16;
  }

  half_t* pw = nullptr; ptrdiff_t wstep = 0;
  if constexpr (WRITE_SEQ) {
    pw = out + ((size_t)sg * DD + ((dir == 0) ? 0 : (len - 1))) * 16 + dir * 8 + li;
    wstep = (dir == 0) ? 16 : -16;
  }

  // epilogue: packed-f16 h-gather + dot2 gh, activations, h update, store
  auto core = [&](float a0, float a1, float a2) {
    float hm = HMIRROR(h);
    int hp = pkh(h, hm);               // {h(own), h(lane^7)}
    f16x2 u0 = bc16(QPERMI(hp, 0));
    f16x2 u1 = bc16(QPERMI(hp, 1));
    f16x2 u2 = bc16(QPERMI(hp, 2));
    f16x2 u3 = bc16(QPERMI(hp, 3));

    float c0 = dot2(bc16(wp[0][3]), u3, dot2(bc16(wp[0][2]), u2,
               dot2(bc16(wp[0][1]), u1, dot2(bc16(wp[0][0]), u0, 0.0f))));
    float c1 = dot2(bc16(wp[1][3]), u3, dot2(bc16(wp[1][2]), u2,
               dot2(bc16(wp[1][1]), u1, dot2(bc16(wp[1][0]), u0, 0.0f))));
    float c2 = dot2(bc16(wp[2][3]), u3, dot2(bc16(wp[2][2]), u2,
               dot2(bc16(wp[2][1]), u1, dot2(bc16(wp[2][0]), u0, bh2))));

    float r = fast_sigmoid(a0 + c0);
    float z = fast_sigmoid(a1 + c1);
    float n = fast_tanh(a2 + r * c2);
    h = z * (h - n) + n;  // == (1-z)*n + z*h
    if constexpr (WRITE_SEQ) { *pw = (half_t)h; pw += wstep; }
  };

  if constexpr (IN_DIM == 1) {
    float s0_, s1_, s2_, s3_;
    auto ld = [&](float& S_) { S_ = *px; px += xstep; };
    auto st = [&](float& S_, bool pf) {
      float a0 = fmaf(wi1[0], S_, bs[0]);
      float a1 = fmaf(wi1[1], S_, bs[1]);
      float a2 = fmaf(wi1[2], S_, bs[2]);
      if (pf) ld(S_);
      core(a0, a1, a2);
    };
    ld(s0_); ld(s1_); ld(s2_); ld(s3_);
    int t = 0;
    for (; t + 4 <= steps; t += 4) {
      st(s0_, true); st(s1_, true); st(s2_, true); st(s3_, true);
    }
    int rem = steps - t;
    if (rem > 0) st(s0_, false);
    if (rem > 1) st(s1_, false);
    if (rem > 2) st(s2_, false);
  } else {
    uint4 b0_[2], b1_[2], b2_[2], b3_[2];
    auto ld = [&](uint4 (&B_)[2]) {
      const uint4* q4 = reinterpret_cast<const uint4*>(pxh);
      B_[0] = q4[0]; B_[1] = q4[1];
      pxh += xstep;
    };
    auto st = [&](uint4 (&B_)[2], bool pf) {
      float a0 = bs[0], a1 = bs[1], a2 = bs[2];
#pragma unroll
      for (int q = 0; q < 2; ++q) {
        f16x2 p0 = __builtin_bit_cast(f16x2, B_[q].x);
        f16x2 p1 = __builtin_bit_cast(f16x2, B_[q].y);
        f16x2 p2 = __builtin_bit_cast(f16x2, B_[q].z);
        f16x2 p3 = __builtin_bit_cast(f16x2, B_[q].w);
        a0 = dot2(wi2[0][4*q], p0, a0); a0 = dot2(wi2[0][4*q+1], p1, a0);
        a0 = dot2(wi2[0][4*q+2], p2, a0); a0 = dot2(wi2[0][4*q+3], p3, a0);
        a1 = dot2(wi2[1][4*q], p0, a1); a1 = dot2(wi2[1][4*q+1], p1, a1);
        a1 = dot2(wi2[1][4*q+2], p2, a1); a1 = dot2(wi2[1][4*q+3], p3, a1);
        a2 = dot2(wi2[2][4*q], p0, a2); a2 = dot2(wi2[2][4*q+1], p1, a2);
        a2 = dot2(wi2[2][4*q+2], p2, a2); a2 = dot2(wi2[2][4*q+3], p3, a2);
      }
      if (pf) ld(B_);
      core(a0, a1, a2);
    };
    ld(b0_); ld(b1_); ld(b2_); ld(b3_);
    int t = 0;
    for (; t + 4 <= steps; t += 4) {
      st(b0_, true); st(b1_, true); st(b2_, true); st(b3_, true);
    }
    int rem = steps - t;
    if (rem > 0) st(b0_, false);
    if (rem > 1) st(b1_, false);
    if (rem > 2) st(b2_, false);
  }

  if constexpr (!WRITE_SEQ) {
    feat[(size_t)order[sg] * 16 + dir * 8 + li] = h;
  }
}

// last layer, bwd direction: only t = len-1 matters and h0 = 0 => gh = bhh
__global__ __launch_bounds__(256) void bwd_last(
    const half_t* __restrict__ in, float* __restrict__ feat,
    const int* __restrict__ len_sorted, const int* __restrict__ order,
    const float* __restrict__ Wih, const float* __restrict__ bih,
    const float* __restrict__ bhh, int nseq) {
  int tid = blockIdx.x * blockDim.x + threadIdx.x;
  int sg = tid >> 3, li = tid & 7;
  if (sg >= nseq) return;
  int len = len_sorted[sg];
  const half_t* xp = in + ((size_t)sg * DD + (len - 1)) * 16;
  float xv[16];
#pragma unroll
  for (int j = 0; j < 16; ++j) xv[j] = (float)xp[j];
  float a[3], bh[3];
#pragma unroll
  for (int gt = 0; gt < 3; ++gt) {
    int row = 24 + gt * 8 + li;  // dir=1 rows
    const float* wpp = Wih + row * 16;
    float acc = bih[row];
#pragma unroll
    for (int j = 0; j < 16; ++j) acc = fmaf(wpp[j], xv[j], acc);
    a[gt] = acc;
    bh[gt] = bhh[row];
  }
  float r = fast_sigmoid(a[0] + bh[0]);
  float z = fast_sigmoid(a[1] + bh[1]);
  float n = fast_tanh(a[2] + r * bh[2]);
  float h = (1.0f - z) * n;
  feat[(size_t)order[sg] * 16 + 8 + li] = h;
}

__global__ __launch_bounds__(256) void head_kernel(
    const float* __restrict__ feat, const float* __restrict__ w1,
    const float* __restrict__ b1, const float* __restrict__ w2,
    const float* __restrict__ b2, float* __restrict__ out) {
  int n = blockIdx.x * blockDim.x + threadIdx.x;
  if (n >= NN) return;
  float f[16];
  const float4* p = reinterpret_cast<const float4*>(feat + (size_t)n * 16);
#pragma unroll
  for (int q = 0; q < 4; ++q) {
    float4 v = p[q];
    f[4*q] = v.x; f[4*q+1] = v.y; f[4*q+2] = v.z; f[4*q+3] = v.w;
  }
  float y[8];
#pragma unroll
  for (int o = 0; o < 8; ++o) {
    float s = b1[o];
#pragma unroll
    for (int j = 0; j < 16; ++j) s += f[j] * w1[o * 16 + j];
    y[o] = (s > 0.0f) ? s : 0.2f * s;
  }
#pragma unroll
  for (int o2 = 0; o2 < 8; ++o2) {
    float s = b2[o2];
#pragma unroll
    for (int o = 0; o < 8; ++o) s += y[o] * w2[o2 * 8 + o];
    out[(size_t)n * 8 + o2] = s;
  }
}

extern "C" void kernel_launch(void* const* d_in, const int* in_sizes, int n_in,
                              void* d_out, int out_size, void* d_ws, size_t ws_size,
                              hipStream_t stream) {
  const float* x      = (const float*)d_in[0];
  const float* w_ih0  = (const float*)d_in[1];
  const float* w_hh0  = (const float*)d_in[2];
  const float* b_ih0  = (const float*)d_in[3];
  const float* b_hh0  = (const float*)d_in[4];
  const float* w_ih   = (const float*)d_in[5];
  const float* w_hh   = (const float*)d_in[6];
  const float* b_ih   = (const float*)d_in[7];
  const float* b_hh   = (const float*)d_in[8];
  const float* lin1_w = (const float*)d_in[9];
  const float* lin1_b = (const float*)d_in[10];
  const float* lin2_w = (const float*)d_in[11];
  const float* lin2_b = (const float*)d_in[12];
  float* out = (float*)d_out;

  char* ws = (char*)d_ws;
  size_t off = 0;
  auto alloc = [&](size_t bytes) -> void* {
    void* p = ws + off;
    off += (bytes + 255) & ~(size_t)255;
    return p;
  };
  alloc(1024);  // front guard (backward prefetch overrun)
  float* xt         = (float*)alloc((size_t)NN * DD * sizeof(float) + 1024);
  int*   lengths    = (int*)  alloc((size_t)NN * sizeof(int));
  int*   hist       = (int*)  alloc(NBINS * sizeof(int));
  int*   offs       = (int*)  alloc(NBINS * sizeof(int));
  int*   order      = (int*)  alloc((size_t)NN * sizeof(int));
  int*   len_sorted = (int*)  alloc((size_t)NN * sizeof(int));
  float* feat       = (float*)alloc((size_t)NN * 16 * sizeof(float));
  size_t base = off;
  size_t per_seq = (size_t)DD * 16 * sizeof(half_t) * 2 + 1024;  // two f16 buffers
  int Nc = NN;
  if (base + (size_t)NN * per_seq + 8192 > ws_size) {
    size_t avail = (ws_size > base + 8192) ? (ws_size - base - 8192) : 0;
    size_t nc = avail / per_seq;
    if (nc < 1) nc = 1;
    if (nc > (size_t)NN) nc = NN;
    Nc = (int)nc;
  }
  alloc(1024);  // guard before bufA
  half_t* bufA = (half_t*)alloc((size_t)Nc * DD * 16 * sizeof(half_t) + 1024);
  half_t* bufB = (half_t*)alloc((size_t)Nc * DD * 16 * sizeof(half_t) + 1024);

  hipMemsetAsync(hist, 0, NBINS * sizeof(int), stream);
  dim3 gT(BB, (DD + 31) / 32, (KK + 31) / 32), bT(32, 8, 1);
  hipLaunchKernelGGL(transpose_x, gT, bT, 0, stream, x, xt);
  hipLaunchKernelGGL(compute_lengths, dim3(NN), dim3(64), 0, stream, xt, lengths, hist);
  hipLaunchKernelGGL(scan_offsets, dim3(1), dim3(64), 0, stream, hist, offs);
  hipLaunchKernelGGL(scatter_sort, dim3((NN + 255) / 256), dim3(256), 0, stream,
                     lengths, offs, order, len_sorted);

  for (int s0 = 0; s0 < NN; s0 += Nc) {
    int ns = (NN - s0 < Nc) ? (NN - s0) : Nc;
    int W2 = (ns * 2 + 7) / 8;           // bidir wave count (1 wave per block)
    int W1 = (ns + 7) / 8;               // fwd-only wave count
    int blk1 = (ns * 8 + 255) / 256;     // bwd_last
    gru_scan<1, true, true, false><<<W2, 64, 0, stream>>>(
        (const void*)xt, bufA, nullptr, len_sorted + s0, order + s0,
        w_ih0, w_hh0, b_ih0, b_hh0, ns);
    gru_scan<16, false, true, false><<<W2, 64, 0, stream>>>(
        (const void*)bufA, bufB, nullptr, len_sorted + s0, order + s0,
        w_ih + 0 * 2 * 24 * 16, w_hh + 0 * 2 * 24 * 8,
        b_ih + 0 * 2 * 24, b_hh + 0 * 2 * 24, ns);
    gru_scan<16, false, true, false><<<W2, 64, 0, stream>>>(
        (const void*)bufB, bufA, nullptr, len_sorted + s0, order + s0,
        w_ih + 1 * 2 * 24 * 16, w_hh + 1 * 2 * 24 * 8,
        b_ih + 1 * 2 * 24, b_hh + 1 * 2 * 24, ns);
    gru_scan<16, false, false, true><<<W1, 64, 0, stream>>>(
        (const void*)bufA, nullptr, feat, len_sorted + s0, order + s0,
        w_ih + 2 * 2 * 24 * 16, w_hh + 2 * 2 * 24 * 8,
        b_ih + 2 * 2 * 24, b_hh + 2 * 2 * 24, ns);
    hipLaunchKernelGGL(bwd_last, dim3(blk1), dim3(256), 0, stream,
                       bufA, feat, len_sorted + s0, order + s0,
                       w_ih + 2 * 2 * 24 * 16, b_ih + 2 * 2 * 24, b_hh + 2 * 2 * 24, ns);
  }
  hipLaunchKernelGGL(head_kernel, dim3((NN + 255) / 256), dim3(256), 0, stream,
                     feat, lin1_w, lin1_b, lin2_w, lin2_b, out);
}

// Round 13
// 381.843 us; speedup vs baseline: 1.3672x; 1.0019x over previous
//
#include <hip/hip_runtime.h>

#define BB 32
#define DD 400
#define KK 200
#define NN (BB*KK)
#define NBINS 512
#define NSIMD 1024  // 256 CU x 4 SIMD

typedef _Float16 half_t;
typedef _Float16 f16x2 __attribute__((ext_vector_type(2)));

__device__ __forceinline__ float dot2(f16x2 w, f16x2 v, float acc) {
  return __builtin_amdgcn_fdot2(w, v, acc, false);
}
__device__ __forceinline__ f16x2 bc16(int v) { return __builtin_bit_cast(f16x2, v); }
__device__ __forceinline__ int pkh(float a, float b) {
  return __builtin_bit_cast(int, __builtin_amdgcn_cvt_pkrtz(a, b));
}

__device__ __forceinline__ float fast_sigmoid(float x) {
  float e = __builtin_amdgcn_exp2f(-1.4426950408889634f * x);
  return __builtin_amdgcn_rcpf(1.0f + e);
}
__device__ __forceinline__ float fast_tanh(float x) {
  float e = __builtin_amdgcn_exp2f(-2.8853900817779268f * x);
  return 2.0f * __builtin_amdgcn_rcpf(1.0f + e) - 1.0f;
}

// quad_perm broadcast P within each aligned 4-lane quad (VALU pipe), int form
#define QPERMI(v, P) __builtin_amdgcn_mov_dpp((v), (P)*0x55, 0xF, 0xF, true)
// ROW_HALF_MIRROR: lane i reads lane i^7 within each 8-lane half-row (VALU pipe)
#define HMIRROR(v) __int_as_float(__builtin_amdgcn_mov_dpp(__float_as_int(v), 0x141, 0xF, 0xF, true))

// x (B, D, K) -> xt[(b*K+k)*D + t] = x[b][t][k]
__global__ __launch_bounds__(256) void transpose_x(const float* __restrict__ x,
                                                   float* __restrict__ xt) {
  __shared__ float tile[32][33];
  int b = blockIdx.x, t0 = blockIdx.y * 32, k0 = blockIdx.z * 32;
  int tx = threadIdx.x, ty = threadIdx.y;
#pragma unroll
  for (int i = 0; i < 32; i += 8) {
    int t = t0 + ty + i, k = k0 + tx;
    tile[ty + i][tx] = (t < DD && k < KK) ? x[((size_t)b * DD + t) * KK + k] : 0.0f;
  }
  __syncthreads();
#pragma unroll
  for (int i = 0; i < 32; i += 8) {
    int k = k0 + ty + i, t = t0 + tx;
    if (k < KK && t < DD) xt[((size_t)b * KK + k) * DD + t] = tile[tx][ty + i];
  }
}

// first zero index (else D) per sequence + length histogram
__global__ __launch_bounds__(64) void compute_lengths(const float* __restrict__ xt,
                                                      int* __restrict__ lengths,
                                                      int* __restrict__ hist) {
  int n = blockIdx.x, lane = threadIdx.x;
  int m = DD;
  for (int t = lane; t < DD; t += 64) {
    if (xt[(size_t)n * DD + t] == 0.0f) { m = t; break; }
  }
#pragma unroll
  for (int off = 1; off < 64; off <<= 1) {
    int o = __shfl_xor(m, off, 64);
    m = (o < m) ? o : m;
  }
  if (lane == 0) {
    lengths[n] = m;
    atomicAdd(&hist[m], 1);
  }
}

// wave-parallel exclusive prefix scan over 512 bins (8 bins/lane + shfl scan)
__global__ __launch_bounds__(64) void scan_offsets(const int* __restrict__ hist,
                                                   int* __restrict__ offs) {
  int lane = threadIdx.x;
  int v[8], tot = 0;
#pragma unroll
  for (int i = 0; i < 8; ++i) { v[i] = tot; tot += hist[lane * 8 + i]; }
  int incl = tot;
#pragma unroll
  for (int off = 1; off < 64; off <<= 1) {
    int oth = __shfl_up(incl, off, 64);
    if (lane >= off) incl += oth;
  }
  int excl = incl - tot;
#pragma unroll
  for (int i = 0; i < 8; ++i) offs[lane * 8 + i] = excl + v[i];
}

__global__ __launch_bounds__(256) void scatter_sort(const int* __restrict__ lengths,
                                                    int* __restrict__ offs,
                                                    int* __restrict__ order,
                                                    int* __restrict__ len_sorted) {
  int n = blockIdx.x * 256 + threadIdx.x;
  if (n >= NN) return;
  int len = lengths[n];
  int pos = atomicAdd(&offs[len], 1);
  order[pos] = n;
  len_sorted[pos] = len;
}

// SIMD-aware wave->octet mapping (1 wave per block; XCD round-robin means
// p and p+NSIMD co-reside). Singles get longest octets; pairs sum ~constant.
__device__ __forceinline__ int octet_of_wave(int p, int W) {
  int E = W - NSIMD;
  if (E <= 0) return W - 1 - p;                 // all singles: desc
  if (p >= NSIMD) return p - NSIMD;             // pair minor: shortest E
  if (p >= E) return W - 1 - (p - E);           // singles: longest
  return (W - 1 - NSIMD + E) - p;               // pair major
}

// ===== dir-major slab layout =====
// buf[oct4][t][dir][32] halfs, where oct4 = sg>>2 groups 4 sequences; slot
// (sg&3)*8+li. A wave-step store -> 2 contiguous 64B segments (fwd row t,
// bwd row len-1-t) instead of 8 scattered 16B segments.
// Consumer: seq sg at t reads 16B at +0 (fwd dims) and 16B at +64B (bwd dims).

// 8 lanes per (sorted-seq, dir); lane li owns hidden unit li. 1 wave per block.
// h-exchange + gh fully packed-f16 (cvt_pk + 4 quad_perm + dot2 chains).
template <int IN_DIM, bool IND_IN, bool WRITE_SEQ, bool FWD_ONLY>
__global__ __launch_bounds__(64) void gru_scan(
    const void* __restrict__ in, half_t* __restrict__ out, float* __restrict__ feat,
    const int* __restrict__ len_sorted, const int* __restrict__ order,
    const float* __restrict__ Wih, const float* __restrict__ Whh,
    const float* __restrict__ bih, const float* __restrict__ bhh, int nseq) {
  int p = blockIdx.x;                 // one wave per block
  int lane = threadIdx.x & 63;
  int G = FWD_ONLY ? nseq : nseq * 2;
  int W = (G + 7) >> 3;
  if (p >= W) return;
  int o = octet_of_wave(p, W);
  int gidx = o * 8 + (lane >> 3);
  int li = lane & 7;
  if (gidx >= G) return;
  int sg  = FWD_ONLY ? gidx : (gidx >> 1);
  int dir = FWD_ONLY ? 0 : (gidx & 1);
  int len = len_sorted[sg];

  int qb = li & 4;
  int wp[3][4];       // packed f16x2 {Whh[.,qb+P], Whh[.,(qb+P)^7]}
  f16x2 wi2[3][8];
  float wi1[3];
  float bs[3], bh2;   // bs[0..1] = bih+bhh, bs[2] = bih; bh2 = bhh n-gate
#pragma unroll
  for (int gt = 0; gt < 3; ++gt) {
    int row = dir * 24 + gt * 8 + li;
    if constexpr (IN_DIM == 16) {
#pragma unroll
      for (int q = 0; q < 8; ++q) {
        f16x2 w;
        w.x = (half_t)Wih[row * 16 + 2 * q];
        w.y = (half_t)Wih[row * 16 + 2 * q + 1];
        wi2[gt][q] = w;
      }
    } else {
      wi1[gt] = Wih[row];
    }
#pragma unroll
    for (int P = 0; P < 4; ++P)
      wp[gt][P] = pkh(Whh[row * 8 + qb + P], Whh[row * 8 + ((qb + P) ^ 7)]);
    bs[gt] = bih[row] + ((gt < 2) ? bhh[row] : 0.0f);
    if (gt == 2) bh2 = bhh[row];
  }

  int steps = len;  // >= 200 always
  float h = 0.0f;

  const float* px = nullptr;
  const half_t* pxh = nullptr;
  ptrdiff_t xstep;
  if constexpr (IN_DIM == 1) {
    const float* basep = (const float*)in + (IND_IN ? (size_t)order[sg] * DD : (size_t)sg * DD);
    px = basep + ((dir == 0) ? 0 : (len - 1));
    xstep = (dir == 0) ? 1 : -1;
  } else {
    // slab consumer: row (sg>>2, t), fwd dims at +(sg&3)*8, bwd dims at +64B
    const half_t* basep = (const half_t*)in + (size_t)(sg >> 2) * DD * 64 + (sg & 3) * 8;
    pxh = basep + (size_t)((dir == 0) ? 0 : (len - 1)) * 64;
    xstep = (dir == 0) ? 64 : -64;
  }

  half_t* pw = nullptr; ptrdiff_t wstep = 0;
  if constexpr (WRITE_SEQ) {
    // slab producer: row (sg>>2, tt), slot dir*32 + (sg&3)*8 + li
    pw = out + ((size_t)(sg >> 2) * DD + ((dir == 0) ? 0 : (len - 1))) * 64
             + dir * 32 + (sg & 3) * 8 + li;
    wstep = (dir == 0) ? 64 : -64;
  }

  // epilogue: packed-f16 h-gather + dot2 gh, activations, h update, store
  auto core = [&](float a0, float a1, float a2) {
    float hm = HMIRROR(h);
    int hp = pkh(h, hm);               // {h(own), h(lane^7)}
    f16x2 u0 = bc16(QPERMI(hp, 0));
    f16x2 u1 = bc16(QPERMI(hp, 1));
    f16x2 u2 = bc16(QPERMI(hp, 2));
    f16x2 u3 = bc16(QPERMI(hp, 3));

    float c0 = dot2(bc16(wp[0][3]), u3, dot2(bc16(wp[0][2]), u2,
               dot2(bc16(wp[0][1]), u1, dot2(bc16(wp[0][0]), u0, 0.0f))));
    float c1 = dot2(bc16(wp[1][3]), u3, dot2(bc16(wp[1][2]), u2,
               dot2(bc16(wp[1][1]), u1, dot2(bc16(wp[1][0]), u0, 0.0f))));
    float c2 = dot2(bc16(wp[2][3]), u3, dot2(bc16(wp[2][2]), u2,
               dot2(bc16(wp[2][1]), u1, dot2(bc16(wp[2][0]), u0, bh2))));

    float r = fast_sigmoid(a0 + c0);
    float z = fast_sigmoid(a1 + c1);
    float n = fast_tanh(a2 + r * c2);
    h = z * (h - n) + n;  // == (1-z)*n + z*h
    if constexpr (WRITE_SEQ) { *pw = (half_t)h; pw += wstep; }
  };

  if constexpr (IN_DIM == 1) {
    float s0_, s1_, s2_, s3_;
    auto ld = [&](float& S_) { S_ = *px; px += xstep; };
    auto st = [&](float& S_, bool pf) {
      float a0 = fmaf(wi1[0], S_, bs[0]);
      float a1 = fmaf(wi1[1], S_, bs[1]);
      float a2 = fmaf(wi1[2], S_, bs[2]);
      if (pf) ld(S_);
      core(a0, a1, a2);
    };
    ld(s0_); ld(s1_); ld(s2_); ld(s3_);
    int t = 0;
    for (; t + 4 <= steps; t += 4) {
      st(s0_, true); st(s1_, true); st(s2_, true); st(s3_, true);
    }
    int rem = steps - t;
    if (rem > 0) st(s0_, false);
    if (rem > 1) st(s1_, false);
    if (rem > 2) st(s2_, false);
  } else {
    uint4 b0_[2], b1_[2], b2_[2], b3_[2];
    auto ld = [&](uint4 (&B_)[2]) {
      const uint4* q4 = reinterpret_cast<const uint4*>(pxh);
      B_[0] = q4[0]; B_[1] = q4[4];   // fwd dims, bwd dims (+64B)
      pxh += xstep;
    };
    auto st = [&](uint4 (&B_)[2], bool pf) {
      float a0 = bs[0], a1 = bs[1], a2 = bs[2];
#pragma unroll
      for (int q = 0; q < 2; ++q) {
        f16x2 p0 = __builtin_bit_cast(f16x2, B_[q].x);
        f16x2 p1 = __builtin_bit_cast(f16x2, B_[q].y);
        f16x2 p2 = __builtin_bit_cast(f16x2, B_[q].z);
        f16x2 p3 = __builtin_bit_cast(f16x2, B_[q].w);
        a0 = dot2(wi2[0][4*q], p0, a0); a0 = dot2(wi2[0][4*q+1], p1, a0);
        a0 = dot2(wi2[0][4*q+2], p2, a0); a0 = dot2(wi2[0][4*q+3], p3, a0);
        a1 = dot2(wi2[1][4*q], p0, a1); a1 = dot2(wi2[1][4*q+1], p1, a1);
        a1 = dot2(wi2[1][4*q+2], p2, a1); a1 = dot2(wi2[1][4*q+3], p3, a1);
        a2 = dot2(wi2[2][4*q], p0, a2); a2 = dot2(wi2[2][4*q+1], p1, a2);
        a2 = dot2(wi2[2][4*q+2], p2, a2); a2 = dot2(wi2[2][4*q+3], p3, a2);
      }
      if (pf) ld(B_);
      core(a0, a1, a2);
    };
    ld(b0_); ld(b1_); ld(b2_); ld(b3_);
    int t = 0;
    for (; t + 4 <= steps; t += 4) {
      st(b0_, true); st(b1_, true); st(b2_, true); st(b3_, true);
    }
    int rem = steps - t;
    if (rem > 0) st(b0_, false);
    if (rem > 1) st(b1_, false);
    if (rem > 2) st(b2_, false);
  }

  if constexpr (!WRITE_SEQ) {
    feat[(size_t)order[sg] * 16 + dir * 8 + li] = h;
  }
}

// last layer, bwd direction: only t = len-1 matters and h0 = 0 => gh = bhh
__global__ __launch_bounds__(256) void bwd_last(
    const half_t* __restrict__ in, float* __restrict__ feat,
    const int* __restrict__ len_sorted, const int* __restrict__ order,
    const float* __restrict__ Wih, const float* __restrict__ bih,
    const float* __restrict__ bhh, int nseq) {
  int tid = blockIdx.x * blockDim.x + threadIdx.x;
  int sg = tid >> 3, li = tid & 7;
  if (sg >= nseq) return;
  int len = len_sorted[sg];
  const half_t* xp = in + ((size_t)(sg >> 2) * DD + (len - 1)) * 64 + (sg & 3) * 8;
  float xv[16];
#pragma unroll
  for (int j = 0; j < 8; ++j) { xv[j] = (float)xp[j]; xv[8 + j] = (float)xp[32 + j]; }
  float a[3], bh[3];
#pragma unroll
  for (int gt = 0; gt < 3; ++gt) {
    int row = 24 + gt * 8 + li;  // dir=1 rows
    const float* wpp = Wih + row * 16;
    float acc = bih[row];
#pragma unroll
    for (int j = 0; j < 16; ++j) acc = fmaf(wpp[j], xv[j], acc);
    a[gt] = acc;
    bh[gt] = bhh[row];
  }
  float r = fast_sigmoid(a[0] + bh[0]);
  float z = fast_sigmoid(a[1] + bh[1]);
  float n = fast_tanh(a[2] + r * bh[2]);
  float h = (1.0f - z) * n;
  feat[(size_t)order[sg] * 16 + 8 + li] = h;
}

__global__ __launch_bounds__(256) void head_kernel(
    const float* __restrict__ feat, const float* __restrict__ w1,
    const float* __restrict__ b1, const float* __restrict__ w2,
    const float* __restrict__ b2, float* __restrict__ out) {
  int n = blockIdx.x * blockDim.x + threadIdx.x;
  if (n >= NN) return;
  float f[16];
  const float4* p = reinterpret_cast<const float4*>(feat + (size_t)n * 16);
#pragma unroll
  for (int q = 0; q < 4; ++q) {
    float4 v = p[q];
    f[4*q] = v.x; f[4*q+1] = v.y; f[4*q+2] = v.z; f[4*q+3] = v.w;
  }
  float y[8];
#pragma unroll
  for (int o = 0; o < 8; ++o) {
    float s = b1[o];
#pragma unroll
    for (int j = 0; j < 16; ++j) s += f[j] * w1[o * 16 + j];
    y[o] = (s > 0.0f) ? s : 0.2f * s;
  }
#pragma unroll
  for (int o2 = 0; o2 < 8; ++o2) {
    float s = b2[o2];
#pragma unroll
    for (int o = 0; o < 8; ++o) s += y[o] * w2[o2 * 8 + o];
    out[(size_t)n * 8 + o2] = s;
  }
}

extern "C" void kernel_launch(void* const* d_in, const int* in_sizes, int n_in,
                              void* d_out, int out_size, void* d_ws, size_t ws_size,
                              hipStream_t stream) {
  const float* x      = (const float*)d_in[0];
  const float* w_ih0  = (const float*)d_in[1];
  const float* w_hh0  = (const float*)d_in[2];
  const float* b_ih0  = (const float*)d_in[3];
  const float* b_hh0  = (const float*)d_in[4];
  const float* w_ih   = (const float*)d_in[5];
  const float* w_hh   = (const float*)d_in[6];
  const float* b_ih   = (const float*)d_in[7];
  const float* b_hh   = (const float*)d_in[8];
  const float* lin1_w = (const float*)d_in[9];
  const float* lin1_b = (const float*)d_in[10];
  const float* lin2_w = (const float*)d_in[11];
  const float* lin2_b = (const float*)d_in[12];
  float* out = (float*)d_out;

  char* ws = (char*)d_ws;
  size_t off = 0;
  auto alloc = [&](size_t bytes) -> void* {
    void* p = ws + off;
    off += (bytes + 255) & ~(size_t)255;
    return p;
  };
  alloc(1024);  // front guard (backward prefetch overrun)
  float* xt         = (float*)alloc((size_t)NN * DD * sizeof(float) + 1024);
  int*   lengths    = (int*)  alloc((size_t)NN * sizeof(int));
  int*   hist       = (int*)  alloc(NBINS * sizeof(int));
  int*   offs       = (int*)  alloc(NBINS * sizeof(int));
  int*   order      = (int*)  alloc((size_t)NN * sizeof(int));
  int*   len_sorted = (int*)  alloc((size_t)NN * sizeof(int));
  float* feat       = (float*)alloc((size_t)NN * 16 * sizeof(float));
  size_t base = off;
  size_t per_seq = (size_t)DD * 16 * sizeof(half_t) * 2 + 1024;  // two f16 buffers
  int Nc = NN;
  if (base + (size_t)NN * per_seq + 8192 > ws_size) {
    size_t avail = (ws_size > base + 8192) ? (ws_size - base - 8192) : 0;
    size_t nc = avail / per_seq;
    if (nc < 4) nc = 4;
    if (nc > (size_t)NN) nc = NN;
    Nc = (int)(nc & ~(size_t)3);  // multiple of 4 (slab oct4 granularity)
  }
  alloc(1024);  // guard before bufA
  half_t* bufA = (half_t*)alloc((size_t)Nc * DD * 16 * sizeof(half_t) + 1024);
  half_t* bufB = (half_t*)alloc((size_t)Nc * DD * 16 * sizeof(half_t) + 1024);

  hipMemsetAsync(hist, 0, NBINS * sizeof(int), stream);
  dim3 gT(BB, (DD + 31) / 32, (KK + 31) / 32), bT(32, 8, 1);
  hipLaunchKernelGGL(transpose_x, gT, bT, 0, stream, x, xt);
  hipLaunchKernelGGL(compute_lengths, dim3(NN), dim3(64), 0, stream, xt, lengths, hist);
  hipLaunchKernelGGL(scan_offsets, dim3(1), dim3(64), 0, stream, hist, offs);
  hipLaunchKernelGGL(scatter_sort, dim3((NN + 255) / 256), dim3(256), 0, stream,
                     lengths, offs, order, len_sorted);

  for (int s0 = 0; s0 < NN; s0 += Nc) {
    int ns = (NN - s0 < Nc) ? (NN - s0) : Nc;
    int W2 = (ns * 2 + 7) / 8;           // bidir wave count (1 wave per block)
    int W1 = (ns + 7) / 8;               // fwd-only wave count
    int blk1 = (ns * 8 + 255) / 256;     // bwd_last
    gru_scan<1, true, true, false><<<W2, 64, 0, stream>>>(
        (const void*)xt, bufA, nullptr, len_sorted + s0, order + s0,
        w_ih0, w_hh0, b_ih0, b_hh0, ns);
    gru_scan<16, false, true, false><<<W2, 64, 0, stream>>>(
        (const void*)bufA, bufB, nullptr, len_sorted + s0, order + s0,
        w_ih + 0 * 2 * 24 * 16, w_hh + 0 * 2 * 24 * 8,
        b_ih + 0 * 2 * 24, b_hh + 0 * 2 * 24, ns);
    gru_scan<16, false, true, false><<<W2, 64, 0, stream>>>(
        (const void*)bufB, bufA, nullptr, len_sorted + s0, order + s0,
        w_ih + 1 * 2 * 24 * 16, w_hh + 1 * 2 * 24 * 8,
        b_ih + 1 * 2 * 24, b_hh + 1 * 2 * 24, ns);
    gru_scan<16, false, false, true><<<W1, 64, 0, stream>>>(
        (const void*)bufA, nullptr, feat, len_sorted + s0, order + s0,
        w_ih + 2 * 2 * 24 * 16, w_hh + 2 * 2 * 24 * 8,
        b_ih + 2 * 2 * 24, b_hh + 2 * 2 * 24, ns);
    hipLaunchKernelGGL(bwd_last, dim3(blk1), dim3(256), 0, stream,
                       bufA, feat, len_sorted + s0, order + s0,
                       w_ih + 2 * 2 * 24 * 16, b_ih + 2 * 2 * 24, b_hh + 2 * 2 * 24, ns);
  }
  hipLaunchKernelGGL(head_kernel, dim3((NN + 255) / 256), dim3(256), 0, stream,
                     feat, lin1_w, lin1_b, lin2_w, lin2_b, out);
}